// Round 1
// baseline (365.645 us; speedup 1.0000x reference)
//
#include <hip/hip_runtime.h>

// Problem constants
#define Bn   16
#define Fn   48
#define Hn   256
#define Wn   256
#define Kn   7
#define Mn   51

// Tiling
#define TH   32
#define TW   32
#define EXTV 38   // TH + 6  (activation window)
#define INV  44   // TH + 12 (input window)

// Workspace layout (in floats)
#define WS_SUMSQ 0        // 16 floats: per-batch sum of r^2
#define WS_WN    16       // 2352 floats: normalized conv weights
#define WS_TAB   2368     // 48*3200 float2 = 307200 floats: RBF pair-LUT
// total: 309568 floats = 1.24 MB

__device__ __forceinline__ float waveReduceSum(float v) {
    #pragma unroll
    for (int o = 32; o > 0; o >>= 1) v += __shfl_xor(v, o);
    return v;
}

// Normalize conv weights (mean-subtract, L2-normalize, scale) + zero accumulators.
__global__ __launch_bounds__(64) void prep_kernel(const float* __restrict__ cw,
                                                  const float* __restrict__ scale_f,
                                                  float* __restrict__ ws) {
    int f = blockIdx.x;
    int t = threadIdx.x;
    float v = (t < 49) ? cw[f * 49 + t] : 0.0f;
    float mean = waveReduceSum(v) * (1.0f / 49.0f);
    float c = (t < 49) ? (v - mean) : 0.0f;
    float nrm = sqrtf(waveReduceSum(c * c));
    float o = scale_f[f] * c / (nrm + 1e-12f);
    if (t < 49) ws[WS_WN + f * 49 + t] = o;
    if (f == 0 && t < 16) ws[WS_SUMSQ + t] = 0.0f;
}

// Build per-filter RBF LUT: tab2[f][i] = ( g_f(-100 + i*h), g_f(-100 + (i+1)*h) ), h = 0.0625
__global__ __launch_bounds__(256) void tab_kernel(const float* __restrict__ rw,
                                                  const float* __restrict__ rc,
                                                  float* __restrict__ ws) {
    int f = blockIdx.y;
    int idx = blockIdx.x * 256 + threadIdx.x;
    if (idx >= 3200) return;
    float x0 = -100.0f + 0.0625f * (float)idx;
    float x1 = x0 + 0.0625f;
    float v0 = 0.f, v1 = 0.f;
    for (int m = 0; m < Mn; ++m) {
        float c = rc[m];
        float wm = rw[f * Mn + m];
        float d0 = x0 - c, d1 = x1 - c;
        v0 += wm * __expf(-0.01f * d0 * d0);
        v1 += wm * __expf(-0.01f * d1 * d1);
    }
    float2* tab2 = (float2*)(ws + WS_TAB);
    tab2[f * 3200 + idx] = make_float2(v0, v1);
}

// Fused conv(7x7, sym pad) -> RBF(LUT) -> convT(7x7) -> r = input - convt - net.
// Writes r into `rout` (= d_out) and atomically accumulates sum(r^2) per batch.
__global__ __launch_bounds__(256) void fused_kernel(const float* __restrict__ input,
                                                    const float* __restrict__ net,
                                                    float* __restrict__ ws,
                                                    float* __restrict__ rout) {
    __shared__ float s_in[INV][45];       // stride 45 (bank spread)
    __shared__ float s_a[EXTV][41];       // stride 41 (kills 2-way half-wave alias)
    __shared__ float s_w[Fn * 49];
    __shared__ float s_red[4];

    const int tid = threadIdx.x;
    const int bz = blockIdx.z;
    const int ty0 = blockIdx.y * TH;
    const int tx0 = blockIdx.x * TW;
    const float* img = input + bz * (Hn * Wn);

    for (int k = tid; k < Fn * 49; k += 256) s_w[k] = ws[WS_WN + k];
    for (int k = tid; k < INV * INV; k += 256) {
        int j = k / INV, i = k % INV;
        int gy = ty0 - 6 + j;
        int gx = tx0 - 6 + i;
        gy = (gy < 0) ? (-1 - gy) : ((gy > 255) ? (511 - gy) : gy);  // symmetric pad
        gx = (gx < 0) ? (-1 - gx) : ((gx > 255) ? (511 - gx) : gx);
        s_in[j][i] = img[gy * Wn + gx];
    }
    __syncthreads();

    // z-phase mapping: column strips; strips row0 = {0,7,14,21,28,31} each 7 rows (last overlaps)
    const int zex = tid % 40;
    const int zs = tid / 40;
    const bool zactive = (zs < 6) && (zex < EXTV);
    const int zrow0 = (zs == 5) ? 31 : zs * 7;

    // convT mapping: 32 cols x 8 strips of 4 rows
    const int ox = tid & 31;
    const int oys = (tid >> 5) * 4;

    const float2* tab2 = (const float2*)(ws + WS_TAB);

    float oacc[4] = {0.f, 0.f, 0.f, 0.f};

    for (int f = 0; f < Fn; ++f) {
        float wf[49];
        #pragma unroll
        for (int t = 0; t < 49; ++t) wf[t] = s_w[f * 49 + t];

        if (zactive) {
            float zacc[7];
            #pragma unroll
            for (int t = 0; t < 7; ++t) zacc[t] = 0.f;
            #pragma unroll
            for (int jr0 = 0; jr0 < 13; ++jr0) {
                float x[7];
                #pragma unroll
                for (int q = 0; q < 7; ++q) x[q] = s_in[zrow0 + jr0][zex + q];
                #pragma unroll
                for (int t = 0; t < 7; ++t) {
                    const int ky = jr0 - t;
                    if (ky >= 0 && ky < 7) {
                        float s = 0.f;
                        #pragma unroll
                        for (int q = 0; q < 7; ++q) s = fmaf(x[q], wf[ky * 7 + q], s);
                        zacc[t] += s;
                    }
                }
            }
            const float2* tf = tab2 + f * 3200;
            #pragma unroll
            for (int t = 0; t < 7; ++t) {
                const int row = zrow0 + t;
                float xc = fminf(fmaxf(zacc[t], -100.f), 100.f);
                float tt = (xc + 100.f) * 16.0f;   // in [0, 3200]
                int i = (int)tt;
                i = (i > 3199) ? 3199 : i;
                float frac = tt - (float)i;
                float2 p = tf[i];
                float a = fmaf(frac, p.y - p.x, p.x);
                const int gy = ty0 - 3 + row;
                const int gx = tx0 - 3 + zex;
                const bool valid = (gy >= 0) && (gy < Hn) && (gx >= 0) && (gx < Wn);
                s_a[row][zex] = valid ? a : 0.f;   // zero-pad for the "full" convT
            }
        }
        __syncthreads();

        // convT: out[oy][ox] += sum_{p,q} a[oy+p][ox+q] * w[6-p][6-q]
        #pragma unroll
        for (int jr0 = 0; jr0 < 10; ++jr0) {
            float y[7];
            #pragma unroll
            for (int q = 0; q < 7; ++q) y[q] = s_a[oys + jr0][ox + q];
            #pragma unroll
            for (int t = 0; t < 4; ++t) {
                const int p = jr0 - t;
                if (p >= 0 && p < 7) {
                    float s = 0.f;
                    #pragma unroll
                    for (int q = 0; q < 7; ++q) s = fmaf(y[q], wf[(6 - p) * 7 + (6 - q)], s);
                    oacc[t] += s;
                }
            }
        }
        __syncthreads();
    }

    // epilogue: r = input - convt - net ; write r to rout; accumulate sum(r^2)
    const float* netb = net + bz * (Hn * Wn);
    float* rb = rout + bz * (Hn * Wn);
    float rsq = 0.f;
    #pragma unroll
    for (int t = 0; t < 4; ++t) {
        const int ly = oys + t;
        const int gy = ty0 + ly, gx = tx0 + ox;
        const float iv = s_in[ly + 6][ox + 6];
        const float r = iv - oacc[t] - netb[gy * Wn + gx];
        rb[gy * Wn + gx] = r;
        rsq += r * r;
    }
    rsq = waveReduceSum(rsq);
    const int wid = tid >> 6, lane = tid & 63;
    if (lane == 0) s_red[wid] = rsq;
    __syncthreads();
    if (tid == 0) atomicAdd(&ws[WS_SUMSQ + bz], s_red[0] + s_red[1] + s_red[2] + s_red[3]);
}

// out = net + scale_b * r   (in place on d_out which holds r)
__global__ __launch_bounds__(256) void finalize_kernel(const float* __restrict__ net,
                                                       const float* __restrict__ stdn,
                                                       const float* __restrict__ alpha,
                                                       const float* __restrict__ ws,
                                                       float* __restrict__ out) {
    const int b = blockIdx.y;
    const float sum = ws[WS_SUMSQ + b];
    const float k = __expf(alpha[0]) * stdn[b] * 256.0f;  // sqrt(65536) = 256
    const float nr = sqrtf(sum);
    const float scale = fminf(1.0f, k / (nr + 1e-12f));
    const int base = b * (Hn * Wn) + (blockIdx.x * 256 + threadIdx.x) * 4;
    float4 rv = *(const float4*)(out + base);
    const float4 nv = *(const float4*)(net + base);
    float4 o;
    o.x = fmaf(rv.x, scale, nv.x);
    o.y = fmaf(rv.y, scale, nv.y);
    o.z = fmaf(rv.z, scale, nv.z);
    o.w = fmaf(rv.w, scale, nv.w);
    *(float4*)(out + base) = o;
}

extern "C" void kernel_launch(void* const* d_in, const int* in_sizes, int n_in,
                              void* d_out, int out_size, void* d_ws, size_t ws_size,
                              hipStream_t stream) {
    const float* input = (const float*)d_in[0];
    const float* stdn  = (const float*)d_in[1];
    // d_in[2] = rbf_data (unused by the forward math)
    const float* net   = (const float*)d_in[3];
    const float* cw    = (const float*)d_in[4];
    const float* sf    = (const float*)d_in[5];
    const float* alpha = (const float*)d_in[6];
    const float* rw    = (const float*)d_in[7];
    const float* rc    = (const float*)d_in[8];
    float* out = (float*)d_out;
    float* ws  = (float*)d_ws;

    prep_kernel<<<dim3(Fn), 64, 0, stream>>>(cw, sf, ws);
    tab_kernel<<<dim3(13, Fn), 256, 0, stream>>>(rw, rc, ws);
    fused_kernel<<<dim3(Wn / TW, Hn / TH, Bn), 256, 0, stream>>>(input, net, ws, out);
    finalize_kernel<<<dim3(64, Bn), 256, 0, stream>>>(net, stdn, alpha, ws, out);
}

// Round 2
// 303.504 us; speedup vs baseline: 1.2047x; 1.2047x over previous
//
#include <hip/hip_runtime.h>

// Problem constants
#define Bn   16
#define Fn   48
#define Hn   256
#define Wn   256
#define Mn   51

// Tiling
#define TH   32
#define TW   32
#define SA_ROWS 38
#define SA_S    44          // s_a row stride (floats); 16B-aligned rows, 4-way worst bank alias
#define SA_PLANE (SA_ROWS * SA_S)   // 1672 floats per wave plane
#define SIN_ROWS 44
#define SIN_COLS 48
#define SIN_S   52          // s_in row stride; 16B-aligned rows

// Workspace layout (floats)
#define WS_SUMSQ 0
#define WS_WN    16
#define WS_TAB   2368       // 48*3200 float2

__device__ __forceinline__ float waveReduceSum(float v) {
    #pragma unroll
    for (int o = 32; o > 0; o >>= 1) v += __shfl_xor(v, o);
    return v;
}

__device__ __forceinline__ float sgpr_f(float v) {
    return __uint_as_float(__builtin_amdgcn_readfirstlane(__float_as_uint(v)));
}

__global__ __launch_bounds__(64) void prep_kernel(const float* __restrict__ cw,
                                                  const float* __restrict__ scale_f,
                                                  float* __restrict__ ws) {
    int f = blockIdx.x;
    int t = threadIdx.x;
    float v = (t < 49) ? cw[f * 49 + t] : 0.0f;
    float mean = waveReduceSum(v) * (1.0f / 49.0f);
    float c = (t < 49) ? (v - mean) : 0.0f;
    float nrm = sqrtf(waveReduceSum(c * c));
    float o = scale_f[f] * c / (nrm + 1e-12f);
    if (t < 49) ws[WS_WN + f * 49 + t] = o;
    if (f == 0 && t < 16) ws[WS_SUMSQ + t] = 0.0f;
}

__global__ __launch_bounds__(256) void tab_kernel(const float* __restrict__ rw,
                                                  const float* __restrict__ rc,
                                                  float* __restrict__ ws) {
    int f = blockIdx.y;
    int idx = blockIdx.x * 256 + threadIdx.x;
    if (idx >= 3200) return;
    float x0 = -100.0f + 0.0625f * (float)idx;
    float x1 = x0 + 0.0625f;
    float v0 = 0.f, v1 = 0.f;
    for (int m = 0; m < Mn; ++m) {
        float c = rc[m];
        float wm = rw[f * Mn + m];
        float d0 = x0 - c, d1 = x1 - c;
        v0 += wm * __expf(-0.01f * d0 * d0);
        v1 += wm * __expf(-0.01f * d1 * d1);
    }
    float2* tab2 = (float2*)(ws + WS_TAB);
    tab2[f * 3200 + idx] = make_float2(v0, v1);
}

// One wave owns one filter per round: z(38x38) -> LUT activation -> own s_a plane
// -> convT partials. No block barrier inside the filter loop.
__global__ __launch_bounds__(256) void fused_kernel(const float* __restrict__ input,
                                                    const float* __restrict__ net,
                                                    float* __restrict__ ws,
                                                    float* __restrict__ rout) {
    __shared__ __align__(16) float s_in[SIN_ROWS * SIN_S];
    __shared__ __align__(16) float s_a[4 * SA_PLANE];   // one plane per wave; reused as reduce buf

    const int tid = threadIdx.x;
    const int lane = tid & 63;
    const int wv = tid >> 6;
    const int bz = blockIdx.z;
    const int ty0 = blockIdx.y * TH;
    const int tx0 = blockIdx.x * TW;
    const float* img = input + bz * (Hn * Wn);

    // stage input window: 44 rows x 48 cols, symmetric padding
    for (int k = tid; k < SIN_ROWS * SIN_COLS; k += 256) {
        int j = k / SIN_COLS, i = k % SIN_COLS;
        int gy = ty0 - 6 + j;
        int gx = tx0 - 6 + i;
        gy = (gy < 0) ? (-1 - gy) : ((gy > 255) ? (511 - gy) : gy);
        gx = (gx < 0) ? (-1 - gx) : ((gx > 255) ? (511 - gx) : gx);
        s_in[j * SIN_S + i] = img[gy * Wn + gx];
    }
    __syncthreads();

    // z mapping: 60 active lanes = 10 col-groups (4 cols) x 6 row-strips (7 rows)
    const int cg = lane % 10;
    const int rs = lane / 10;
    const bool zact = (rs < 6);
    const int zr0 = (rs == 5) ? 31 : rs * 7;
    const int zc0 = cg * 4;

    // convT mapping: 64 lanes = 8x8 tiles of 4x4 outputs
    const int tx = (lane & 7) * 4;
    const int ty = (lane >> 3) * 4;

    const float2* tab2 = (const float2*)(ws + WS_TAB);
    const float* wn = ws + WS_WN;
    float* sa = s_a + wv * SA_PLANE;

    float oacc[4][4] = {{0.f}};

    #pragma unroll 1
    for (int fr = 0; fr < 12; ++fr) {
        const int f = fr * 4 + wv;
        const float* wnp = wn + f * 49;
        float wf[49];
        #pragma unroll
        for (int t = 0; t < 49; ++t) wf[t] = sgpr_f(wnp[t]);

        if (zact) {
            float zacc[7][4];
            #pragma unroll
            for (int t = 0; t < 7; ++t)
                #pragma unroll
                for (int c = 0; c < 4; ++c) zacc[t][c] = 0.f;

            #pragma unroll
            for (int jr = 0; jr < 13; ++jr) {
                const float* xr = &s_in[(zr0 + jr) * SIN_S + zc0];
                float4 xa = *(const float4*)xr;
                float4 xb = *(const float4*)(xr + 4);
                float4 xc = *(const float4*)(xr + 8);
                float x[12] = {xa.x, xa.y, xa.z, xa.w, xb.x, xb.y, xb.z, xb.w,
                               xc.x, xc.y, xc.z, xc.w};
                #pragma unroll
                for (int t = 0; t < 7; ++t) {
                    const int ky = jr - t;
                    if (ky >= 0 && ky < 7) {
                        #pragma unroll
                        for (int c = 0; c < 4; ++c) {
                            #pragma unroll
                            for (int q = 0; q < 7; ++q)
                                zacc[t][c] = fmaf(x[c + q], wf[ky * 7 + q], zacc[t][c]);
                        }
                    }
                }
            }

            const float2* tf = tab2 + f * 3200;
            #pragma unroll
            for (int t = 0; t < 7; ++t) {
                const int r = zr0 + t;
                const int gy = ty0 - 3 + r;
                const bool vy = (gy >= 0) && (gy < Hn);
                float av[4];
                #pragma unroll
                for (int c = 0; c < 4; ++c) {
                    const int gx = tx0 - 3 + zc0 + c;
                    float xcl = fminf(fmaxf(zacc[t][c], -100.f), 100.f);
                    float tt = (xcl + 100.f) * 16.0f;
                    int i = (int)tt;
                    i = (i > 3199) ? 3199 : i;
                    float frac = tt - (float)i;
                    float2 p = tf[i];
                    float a = fmaf(frac, p.y - p.x, p.x);
                    av[c] = (vy && gx >= 0 && gx < Wn) ? a : 0.f;
                }
                *(float4*)&sa[r * SA_S + zc0] = make_float4(av[0], av[1], av[2], av[3]);
            }
        }

        __threadfence_block();   // own-wave LDS RAW ordering (no block barrier needed)

        #pragma unroll
        for (int jr = 0; jr < 10; ++jr) {
            const float* yr = &sa[(ty + jr) * SA_S + tx];
            float4 ya = *(const float4*)yr;
            float4 yb = *(const float4*)(yr + 4);
            float4 yc = *(const float4*)(yr + 8);
            float y[12] = {ya.x, ya.y, ya.z, ya.w, yb.x, yb.y, yb.z, yb.w,
                           yc.x, yc.y, yc.z, yc.w};
            #pragma unroll
            for (int t = 0; t < 4; ++t) {
                const int p = jr - t;
                if (p >= 0 && p < 7) {
                    #pragma unroll
                    for (int c = 0; c < 4; ++c) {
                        #pragma unroll
                        for (int q = 0; q < 7; ++q)
                            oacc[t][c] = fmaf(y[c + q], wf[(6 - p) * 7 + (6 - q)], oacc[t][c]);
                    }
                }
            }
        }
        __threadfence_block();   // WAR: next round's z writes vs this round's reads
    }

    // cross-wave reduction of oacc partials
    __syncthreads();
    if (wv > 0) {
        #pragma unroll
        for (int t = 0; t < 4; ++t)
            #pragma unroll
            for (int c = 0; c < 4; ++c)
                s_a[(((wv - 1) * 16) + t * 4 + c) * 64 + lane] = oacc[t][c];
    }
    __syncthreads();

    if (wv == 0) {
        const float* netb = net + bz * (Hn * Wn);
        float* rb = rout + bz * (Hn * Wn);
        float rsq = 0.f;
        #pragma unroll
        for (int t = 0; t < 4; ++t) {
            const int oy = ty + t;
            const int gy = ty0 + oy;
            float4 nv = *(const float4*)&netb[gy * Wn + tx0 + tx];
            float rv[4];
            #pragma unroll
            for (int c = 0; c < 4; ++c) {
                float cv = oacc[t][c]
                         + s_a[(0 * 16 + t * 4 + c) * 64 + lane]
                         + s_a[(1 * 16 + t * 4 + c) * 64 + lane]
                         + s_a[(2 * 16 + t * 4 + c) * 64 + lane];
                const float iv = s_in[(oy + 6) * SIN_S + tx + 6 + c];
                const float nvc = (c == 0) ? nv.x : (c == 1) ? nv.y : (c == 2) ? nv.z : nv.w;
                float r = iv - cv - nvc;
                rv[c] = r;
                rsq += r * r;
            }
            *(float4*)&rb[gy * Wn + tx0 + tx] = make_float4(rv[0], rv[1], rv[2], rv[3]);
        }
        rsq = waveReduceSum(rsq);
        if (lane == 0) atomicAdd(&ws[WS_SUMSQ + bz], rsq);
    }
}

__global__ __launch_bounds__(256) void finalize_kernel(const float* __restrict__ net,
                                                       const float* __restrict__ stdn,
                                                       const float* __restrict__ alpha,
                                                       const float* __restrict__ ws,
                                                       float* __restrict__ out) {
    const int b = blockIdx.y;
    const float sum = ws[WS_SUMSQ + b];
    const float k = __expf(alpha[0]) * stdn[b] * 256.0f;
    const float nr = sqrtf(sum);
    const float scale = fminf(1.0f, k / (nr + 1e-12f));
    const int base = b * (Hn * Wn) + (blockIdx.x * 256 + threadIdx.x) * 4;
    float4 rv = *(const float4*)(out + base);
    const float4 nv = *(const float4*)(net + base);
    float4 o;
    o.x = fmaf(rv.x, scale, nv.x);
    o.y = fmaf(rv.y, scale, nv.y);
    o.z = fmaf(rv.z, scale, nv.z);
    o.w = fmaf(rv.w, scale, nv.w);
    *(float4*)(out + base) = o;
}

extern "C" void kernel_launch(void* const* d_in, const int* in_sizes, int n_in,
                              void* d_out, int out_size, void* d_ws, size_t ws_size,
                              hipStream_t stream) {
    const float* input = (const float*)d_in[0];
    const float* stdn  = (const float*)d_in[1];
    const float* net   = (const float*)d_in[3];
    const float* cw    = (const float*)d_in[4];
    const float* sf    = (const float*)d_in[5];
    const float* alpha = (const float*)d_in[6];
    const float* rw    = (const float*)d_in[7];
    const float* rc    = (const float*)d_in[8];
    float* out = (float*)d_out;
    float* ws  = (float*)d_ws;

    prep_kernel<<<dim3(Fn), 64, 0, stream>>>(cw, sf, ws);
    tab_kernel<<<dim3(13, Fn), 256, 0, stream>>>(rw, rc, ws);
    fused_kernel<<<dim3(Wn / TW, Hn / TH, Bn), 256, 0, stream>>>(input, net, ws, out);
    finalize_kernel<<<dim3(64, Bn), 256, 0, stream>>>(net, stdn, alpha, ws, out);
}